// Round 5
// baseline (2054.605 us; speedup 1.0000x reference)
//
#include <hip/hip_runtime.h>
#include <math.h>

#define KTOT   1024
#define DIM    64
#define NROWS  (64 * 4096)
#define BLOCK  512          // 8 waves: 2 K-halves x 256 rows/block
#define ROWSPB 256          // rows per block
#define NPART  (NROWS / ROWSPB)   // 1024 loss partials (ws layout unchanged)

// ws layout: [0,1024) float loss partials; [1024,2048) float inv_esq  (8 KB)

__global__ __launch_bounds__(256) void vq_prep(const float* __restrict__ emb,
                                               float* __restrict__ inv_esq) {
    int k = blockIdx.x * 256 + threadIdx.x;
    if (k < KTOT) {
        const float4* e4 = (const float4*)(emb + (size_t)k * DIM);
        float s = 0.f;
#pragma unroll
        for (int i = 0; i < DIM / 4; ++i) {
            float4 v = e4[i];
            s += v.x * v.x;
            s += v.y * v.y;
            s += v.z * v.z;
            s += v.w * v.w;
        }
        inv_esq[k] = 1.0f / s;
    }
}

__global__ __launch_bounds__(BLOCK) void vq_main(const float* __restrict__ z_e,
                                                 const float* __restrict__ emb,
                                                 const float* __restrict__ inv_esq,
                                                 float* __restrict__ out_zq,
                                                 float* __restrict__ out_idx,
                                                 float* __restrict__ partials) {
    __shared__ float s_best[ROWSPB];   // half-1 results
    __shared__ int   s_bestk[ROWSPB];
    __shared__ float wred[BLOCK / 64];

    const int tid = threadIdx.x;
    const int rowLocal = tid & (ROWSPB - 1);
    const int half = tid >> 8;                       // 0: k in [0,512)  1: [512,1024)
    const size_t row = (size_t)blockIdx.x * ROWSPB + rowLocal;

    // z row -> 64 VGPRs (each K-half thread loads its row; L1/L2 absorbs the dup)
    float z[DIM];
    {
        const float4* zp = (const float4*)(z_e + row * DIM);
#pragma unroll
        for (int i = 0; i < DIM / 4; ++i) *(float4*)&z[4 * i] = zp[i];
    }

    float best = -INFINITY;
    int bestk = 0;

    const int k0 = half * (KTOT / 2);
    const int k1 = k0 + (KTOT / 2);

    // Latency hiding is TLP: 8 waves/block, ~6 waves/SIMD resident. Loads are
    // wave-uniform (broadcast); 2 interleaved FMA chains saturate issue.
#pragma unroll 2
    for (int k = k0; k < k1; ++k) {
        const float4* e4 = (const float4*)(emb + (size_t)k * DIM);
        float a0 = 0.f, a1 = 0.f;
#pragma unroll
        for (int i = 0; i < 16; i += 2) {
            float4 v0 = e4[i];
            float4 v1 = e4[i + 1];
            a0 = fmaf(z[4 * i + 0], v0.x, a0);
            a1 = fmaf(z[4 * i + 4], v1.x, a1);
            a0 = fmaf(z[4 * i + 1], v0.y, a0);
            a1 = fmaf(z[4 * i + 5], v1.y, a1);
            a0 = fmaf(z[4 * i + 2], v0.z, a0);
            a1 = fmaf(z[4 * i + 6], v1.z, a1);
            a0 = fmaf(z[4 * i + 3], v0.w, a0);
            a1 = fmaf(z[4 * i + 7], v1.w, a1);
        }
        float dot = a0 + a1;
        // dist = (z_sq/e_sq[k]/(-2)) * dot ; z_sq>0 => argmin dist == argmax dot/e_sq
        float q = dot * inv_esq[k];
        bool b = q > best;                 // strict >: first-max == argmin-first
        bestk = b ? k : bestk;
        best = fmaxf(q, best);
    }

    // Merge K-halves: half-1 publishes, half-0 combines (strict > keeps the
    // lower-k winner on ties -> global argmin-first semantics preserved).
    if (half == 1) {
        s_best[rowLocal] = best;
        s_bestk[rowLocal] = bestk;
    }
    __syncthreads();

    float lsum = 0.f;
    if (half == 0) {
        float q1 = s_best[rowLocal];
        int kk1 = s_bestk[rowLocal];
        if (q1 > best) { best = q1; bestk = kk1; }

        // Epilogue: gather z_q, straight-through output, loss partial.
        const float4* eb = (const float4*)(emb + (size_t)bestk * DIM);
        float4* oz = (float4*)(out_zq + row * DIM);
#pragma unroll
        for (int i = 0; i < 16; ++i) {
            float4 e = eb[i];
            float4 zz = *(const float4*)&z[4 * i];
            float dx = e.x - zz.x, dy = e.y - zz.y, dz = e.z - zz.z, dw = e.w - zz.w;
            float4 o;
            o.x = zz.x + dx;  // z_e + (z_q - z_e): matches reference rounding
            o.y = zz.y + dy;
            o.z = zz.z + dz;
            o.w = zz.w + dw;
            oz[i] = o;
            lsum = fmaf(dx, dx, lsum);
            lsum = fmaf(dy, dy, lsum);
            lsum = fmaf(dz, dz, lsum);
            lsum = fmaf(dw, dw, lsum);
        }
        out_idx[row] = (float)bestk;
    }

    // Deterministic block reduction (half-1 lanes contribute 0).
#pragma unroll
    for (int off = 32; off > 0; off >>= 1) lsum += __shfl_down(lsum, off);
    if ((tid & 63) == 0) wred[tid >> 6] = lsum;
    __syncthreads();
    if (tid == 0) {
        float t = 0.f;
#pragma unroll
        for (int i = 0; i < BLOCK / 64; ++i) t += wred[i];
        partials[blockIdx.x] = t;
    }
}

__global__ __launch_bounds__(256) void vq_finalize(const float* __restrict__ partials,
                                                   float* __restrict__ out_loss) {
    __shared__ double wredd[4];
    int tid = threadIdx.x;
    double s = 0.0;
    for (int i = tid; i < NPART; i += 256) s += (double)partials[i];
#pragma unroll
    for (int off = 32; off > 0; off >>= 1) s += __shfl_down(s, off);
    if ((tid & 63) == 0) wredd[tid >> 6] = s;
    __syncthreads();
    if (tid == 0) {
        double tot = (wredd[0] + wredd[1]) + (wredd[2] + wredd[3]);
        float m = (float)(tot / 16777216.0);   // mean over 64*4096*64 elements
        out_loss[0] = m + 0.25f * m;           // m + beta*m, matching reference order
    }
}

extern "C" void kernel_launch(void* const* d_in, const int* in_sizes, int n_in,
                              void* d_out, int out_size, void* d_ws, size_t ws_size,
                              hipStream_t stream) {
    const float* z_e = (const float*)d_in[0];
    const float* emb = (const float*)d_in[1];

    float* out = (float*)d_out;
    float* out_zq = out;                              // 16,777,216 floats
    float* out_idx = out + (size_t)NROWS * DIM;       // 262,144 floats (indices as float)
    float* out_loss = out_idx + NROWS;                // 1 float

    float* partials = (float*)d_ws;                   // 1024 floats
    float* inv_esq = partials + NPART;                // 1024 floats

    vq_prep<<<(KTOT + 255) / 256, 256, 0, stream>>>(emb, inv_esq);
    vq_main<<<NROWS / ROWSPB, BLOCK, 0, stream>>>(z_e, emb, inv_esq, out_zq, out_idx, partials);
    vq_finalize<<<1, 256, 0, stream>>>(partials, out_loss);
}

// Round 7
// 1669.770 us; speedup vs baseline: 1.2305x; 1.2305x over previous
//
#include <hip/hip_runtime.h>
#include <math.h>

#define KTOT   1024
#define DIM    64
#define NROWS  (64 * 4096)
#define BLOCK  256

// ws layout: [0,1024) float loss partials; [1024,2048) float inv_esq  (8 KB)

__global__ __launch_bounds__(BLOCK) void vq_prep(const float* __restrict__ emb,
                                                 float* __restrict__ inv_esq) {
    int k = blockIdx.x * BLOCK + threadIdx.x;
    if (k < KTOT) {
        const float4* e4 = (const float4*)(emb + (size_t)k * DIM);
        float s = 0.f;
#pragma unroll
        for (int i = 0; i < DIM / 4; ++i) {
            float4 v = e4[i];
            s += v.x * v.x;
            s += v.y * v.y;
            s += v.z * v.z;
            s += v.w * v.w;
        }
        inv_esq[k] = 1.0f / s;
    }
}

__global__ __launch_bounds__(BLOCK) void vq_main(const float* __restrict__ z_e,
                                                 const float* __restrict__ emb,
                                                 const float* __restrict__ inv_esq,
                                                 float* __restrict__ out_zq,
                                                 float* __restrict__ out_idx,
                                                 float* __restrict__ partials) {
    __shared__ float wred[BLOCK / 64];

    const int tid = threadIdx.x;
    const size_t row = (size_t)blockIdx.x * BLOCK + tid;

    // z row in 16 float4 registers. No type-punning (round-4's *(float4*)&z[..]
    // blocked SROA -> z went to scratch -> 168 GB/dispatch scratch traffic and
    // exposed per-iteration memory latency). All indices below are literal
    // after full unroll -> SROA keeps zf in 64 VGPRs.
    float4 zf[16];
    {
        const float4* zp = (const float4*)(z_e + row * DIM);
#pragma unroll
        for (int i = 0; i < 16; ++i) zf[i] = zp[i];
    }

    float best = -INFINITY;
    int bestk = 0;

    // k and all codebook addresses are wave-uniform (loop counter + literal
    // offsets only) -> scalar s_load path (SGPR operands feed v_fma directly).
#pragma unroll 2
    for (int k = 0; k < KTOT; ++k) {
        const float4* e4 = (const float4*)(emb + (size_t)k * DIM);
        float a0 = 0.f, a1 = 0.f;
#pragma unroll
        for (int i = 0; i < 16; i += 2) {
            float4 v0 = e4[i];
            float4 v1 = e4[i + 1];
            a0 = fmaf(zf[i].x, v0.x, a0);
            a1 = fmaf(zf[i + 1].x, v1.x, a1);
            a0 = fmaf(zf[i].y, v0.y, a0);
            a1 = fmaf(zf[i + 1].y, v1.y, a1);
            a0 = fmaf(zf[i].z, v0.z, a0);
            a1 = fmaf(zf[i + 1].z, v1.z, a1);
            a0 = fmaf(zf[i].w, v0.w, a0);
            a1 = fmaf(zf[i + 1].w, v1.w, a1);
        }
        float dot = a0 + a1;
        // dist = (z_sq/e_sq[k]/(-2)) * dot ; z_sq>0 => argmin dist == argmax dot/e_sq
        float q = dot * inv_esq[k];
        bool b = q > best;                 // strict >: first-max == argmin-first
        bestk = b ? k : bestk;
        best = fmaxf(q, best);
    }

    // Epilogue: gather z_q, straight-through output, loss partial.
    const float4* eb = (const float4*)(emb + (size_t)bestk * DIM);
    float4* oz = (float4*)(out_zq + row * DIM);
    float lsum = 0.f;
#pragma unroll
    for (int i = 0; i < 16; ++i) {
        float4 e = eb[i];
        float4 zz = zf[i];
        float dx = e.x - zz.x, dy = e.y - zz.y, dz = e.z - zz.z, dw = e.w - zz.w;
        float4 o;
        o.x = zz.x + dx;  // z_e + (z_q - z_e): matches reference rounding
        o.y = zz.y + dy;
        o.z = zz.z + dz;
        o.w = zz.w + dw;
        oz[i] = o;
        lsum = fmaf(dx, dx, lsum);
        lsum = fmaf(dy, dy, lsum);
        lsum = fmaf(dz, dz, lsum);
        lsum = fmaf(dw, dw, lsum);
    }
    out_idx[row] = (float)bestk;

    // Deterministic block reduction of loss partial (no atomics).
#pragma unroll
    for (int off = 32; off > 0; off >>= 1) lsum += __shfl_down(lsum, off);
    if ((tid & 63) == 0) wred[tid >> 6] = lsum;
    __syncthreads();
    if (tid == 0) partials[blockIdx.x] = (wred[0] + wred[1]) + (wred[2] + wred[3]);
}

__global__ __launch_bounds__(BLOCK) void vq_finalize(const float* __restrict__ partials,
                                                     float* __restrict__ out_loss) {
    __shared__ double wredd[BLOCK / 64];
    int tid = threadIdx.x;
    double s = 0.0;
    for (int i = tid; i < NROWS / BLOCK; i += BLOCK) s += (double)partials[i];
#pragma unroll
    for (int off = 32; off > 0; off >>= 1) s += __shfl_down(s, off);
    if ((tid & 63) == 0) wredd[tid >> 6] = s;
    __syncthreads();
    if (tid == 0) {
        double tot = (wredd[0] + wredd[1]) + (wredd[2] + wredd[3]);
        float m = (float)(tot / 16777216.0);   // mean over 64*4096*64 elements
        out_loss[0] = m + 0.25f * m;           // m + beta*m, matching reference order
    }
}

extern "C" void kernel_launch(void* const* d_in, const int* in_sizes, int n_in,
                              void* d_out, int out_size, void* d_ws, size_t ws_size,
                              hipStream_t stream) {
    const float* z_e = (const float*)d_in[0];
    const float* emb = (const float*)d_in[1];

    float* out = (float*)d_out;
    float* out_zq = out;                              // 16,777,216 floats
    float* out_idx = out + (size_t)NROWS * DIM;       // 262,144 floats (indices as float)
    float* out_loss = out_idx + NROWS;                // 1 float

    float* partials = (float*)d_ws;                   // 1024 floats
    float* inv_esq = partials + (NROWS / BLOCK);      // 1024 floats

    vq_prep<<<(KTOT + BLOCK - 1) / BLOCK, BLOCK, 0, stream>>>(emb, inv_esq);
    vq_main<<<NROWS / BLOCK, BLOCK, 0, stream>>>(z_e, emb, inv_esq, out_zq, out_idx, partials);
    vq_finalize<<<1, BLOCK, 0, stream>>>(partials, out_loss);
}

// Round 8
// 1078.649 us; speedup vs baseline: 1.9048x; 1.5480x over previous
//
#include <hip/hip_runtime.h>
#include <math.h>

#define KTOT   1024
#define DIM    64
#define NROWS  (64 * 4096)
#define BLOCK  256
#define CHUNK  128

// ws layout: [0,1024) float loss partials; [1024,2048) float inv_esq  (8 KB)

__global__ __launch_bounds__(BLOCK) void vq_prep(const float* __restrict__ emb,
                                                 float* __restrict__ inv_esq) {
    int k = blockIdx.x * BLOCK + threadIdx.x;
    if (k < KTOT) {
        const float4* e4 = (const float4*)(emb + (size_t)k * DIM);
        float s = 0.f;
#pragma unroll
        for (int i = 0; i < DIM / 4; ++i) {
            float4 v = e4[i];
            s += v.x * v.x;
            s += v.y * v.y;
            s += v.z * v.z;
            s += v.w * v.w;
        }
        inv_esq[k] = 1.0f / s;
    }
}

// Broadcast source = LDS, not SMEM. Rationale (rounds 4/7 evidence): scalarized
// codebook s_loads serialize on SGPR pressure (64-SGPR row vs ~102 cap -> 4
// lgkmcnt(0) drains/k, ~1200 cyc exposed vs 140 cyc compute, VALUBusy 17%).
// ds_read is in-order -> counted lgkmcnt waits -> latency hides under FMAs.
__global__ __launch_bounds__(BLOCK) void vq_main(const float* __restrict__ z_e,
                                                 const float* __restrict__ emb,
                                                 const float* __restrict__ inv_esq,
                                                 float* __restrict__ out_zq,
                                                 float* __restrict__ out_idx,
                                                 float* __restrict__ partials) {
    __shared__ float e_lds[CHUNK * DIM];   // 32 KB codebook chunk
    __shared__ float r_lds[CHUNK];
    __shared__ float wred[BLOCK / 64];

    const int tid = threadIdx.x;
    const size_t row = (size_t)blockIdx.x * BLOCK + tid;

    // z row in 16 float4 registers (literal indices only -> SROA-safe).
    float4 zf[16];
    {
        const float4* zp = (const float4*)(z_e + row * DIM);
#pragma unroll
        for (int i = 0; i < 16; ++i) zf[i] = zp[i];
    }

    float best = -INFINITY;
    int bestk = 0;

    for (int c = 0; c < KTOT; c += CHUNK) {
        // Stage 128 codebook rows: 2048 float4, 8 per thread, coalesced.
        {
            const float4* eg = (const float4*)(emb + (size_t)c * DIM);
            float4* el = (float4*)e_lds;
#pragma unroll
            for (int i = 0; i < (CHUNK * DIM / 4) / BLOCK; ++i)
                el[tid + i * BLOCK] = eg[tid + i * BLOCK];
            if (tid < CHUNK) r_lds[tid] = inv_esq[c + tid];
        }
        __syncthreads();

#pragma unroll 2
        for (int kk = 0; kk < CHUNK; ++kk) {
            const float4* e4 = (const float4*)(e_lds + kk * DIM);  // uniform -> broadcast, 0 conflicts
            float a0 = 0.f, a1 = 0.f;
#pragma unroll
            for (int i = 0; i < 16; i += 2) {
                float4 v0 = e4[i];
                float4 v1 = e4[i + 1];
                a0 = fmaf(zf[i].x, v0.x, a0);
                a1 = fmaf(zf[i + 1].x, v1.x, a1);
                a0 = fmaf(zf[i].y, v0.y, a0);
                a1 = fmaf(zf[i + 1].y, v1.y, a1);
                a0 = fmaf(zf[i].z, v0.z, a0);
                a1 = fmaf(zf[i + 1].z, v1.z, a1);
                a0 = fmaf(zf[i].w, v0.w, a0);
                a1 = fmaf(zf[i + 1].w, v1.w, a1);
            }
            float dot = a0 + a1;
            // dist = (z_sq/e_sq[k]/(-2))*dot ; z_sq>0 => argmin dist == argmax dot/e_sq
            float q = dot * r_lds[kk];
            bool b = q > best;               // strict >: first-max == argmin-first
            bestk = b ? (c + kk) : bestk;
            best = fmaxf(q, best);
        }
        __syncthreads();
    }

    // Epilogue: gather z_q, straight-through output, loss partial.
    const float4* eb = (const float4*)(emb + (size_t)bestk * DIM);
    float4* oz = (float4*)(out_zq + row * DIM);
    float lsum = 0.f;
#pragma unroll
    for (int i = 0; i < 16; ++i) {
        float4 e = eb[i];
        float4 zz = zf[i];
        float dx = e.x - zz.x, dy = e.y - zz.y, dz = e.z - zz.z, dw = e.w - zz.w;
        float4 o;
        o.x = zz.x + dx;  // z_e + (z_q - z_e): matches reference rounding
        o.y = zz.y + dy;
        o.z = zz.z + dz;
        o.w = zz.w + dw;
        oz[i] = o;
        lsum = fmaf(dx, dx, lsum);
        lsum = fmaf(dy, dy, lsum);
        lsum = fmaf(dz, dz, lsum);
        lsum = fmaf(dw, dw, lsum);
    }
    out_idx[row] = (float)bestk;

    // Deterministic block reduction of loss partial (no atomics).
#pragma unroll
    for (int off = 32; off > 0; off >>= 1) lsum += __shfl_down(lsum, off);
    if ((tid & 63) == 0) wred[tid >> 6] = lsum;
    __syncthreads();
    if (tid == 0) partials[blockIdx.x] = (wred[0] + wred[1]) + (wred[2] + wred[3]);
}

__global__ __launch_bounds__(BLOCK) void vq_finalize(const float* __restrict__ partials,
                                                     float* __restrict__ out_loss) {
    __shared__ double wredd[BLOCK / 64];
    int tid = threadIdx.x;
    double s = 0.0;
    for (int i = tid; i < NROWS / BLOCK; i += BLOCK) s += (double)partials[i];
#pragma unroll
    for (int off = 32; off > 0; off >>= 1) s += __shfl_down(s, off);
    if ((tid & 63) == 0) wredd[tid >> 6] = s;
    __syncthreads();
    if (tid == 0) {
        double tot = (wredd[0] + wredd[1]) + (wredd[2] + wredd[3]);
        float m = (float)(tot / 16777216.0);   // mean over 64*4096*64 elements
        out_loss[0] = m + 0.25f * m;           // m + beta*m, matching reference order
    }
}

extern "C" void kernel_launch(void* const* d_in, const int* in_sizes, int n_in,
                              void* d_out, int out_size, void* d_ws, size_t ws_size,
                              hipStream_t stream) {
    const float* z_e = (const float*)d_in[0];
    const float* emb = (const float*)d_in[1];

    float* out = (float*)d_out;
    float* out_zq = out;                              // 16,777,216 floats
    float* out_idx = out + (size_t)NROWS * DIM;       // 262,144 floats (indices as float)
    float* out_loss = out_idx + NROWS;                // 1 float

    float* partials = (float*)d_ws;                   // 1024 floats
    float* inv_esq = partials + (NROWS / BLOCK);      // 1024 floats

    vq_prep<<<(KTOT + BLOCK - 1) / BLOCK, BLOCK, 0, stream>>>(emb, inv_esq);
    vq_main<<<NROWS / BLOCK, BLOCK, 0, stream>>>(z_e, emb, inv_esq, out_zq, out_idx, partials);
    vq_finalize<<<1, BLOCK, 0, stream>>>(partials, out_loss);
}

// Round 10
// 1050.817 us; speedup vs baseline: 1.9552x; 1.0265x over previous
//
#include <hip/hip_runtime.h>
#include <math.h>

#define KTOT   1024
#define DIM    64
#define NROWS  (64 * 4096)
#define BLOCK  256
#define CHUNK  64   // r8 ran CHUNK=128 (33.8 KB LDS) -> only 2 blocks/CU resident
                    // vs the grid ceiling of 4. 16.9 KB doubles residency: TLP
                    // is the discriminating variable this round.

// ws layout: [0,1024) float loss partials; [1024,2048) float inv_esq  (8 KB)

__global__ __launch_bounds__(BLOCK) void vq_prep(const float* __restrict__ emb,
                                                 float* __restrict__ inv_esq) {
    int k = blockIdx.x * BLOCK + threadIdx.x;
    if (k < KTOT) {
        const float4* e4 = (const float4*)(emb + (size_t)k * DIM);
        float s = 0.f;
#pragma unroll
        for (int i = 0; i < DIM / 4; ++i) {
            float4 v = e4[i];
            s += v.x * v.x;
            s += v.y * v.y;
            s += v.z * v.z;
            s += v.w * v.w;
        }
        inv_esq[k] = 1.0f / s;
    }
}

// LDS broadcast loop (r8: 1550->1123 µs vs SMEM). ds_read is in-order ->
// counted lgkmcnt -> latency hides under FMAs, given enough resident waves.
__global__ __launch_bounds__(BLOCK) void vq_main(const float* __restrict__ z_e,
                                                 const float* __restrict__ emb,
                                                 const float* __restrict__ inv_esq,
                                                 float* __restrict__ out_zq,
                                                 float* __restrict__ out_idx,
                                                 float* __restrict__ partials) {
    __shared__ float e_lds[CHUNK * DIM];   // 16 KB codebook chunk
    __shared__ float r_lds[CHUNK];
    __shared__ float wred[BLOCK / 64];

    const int tid = threadIdx.x;
    const size_t row = (size_t)blockIdx.x * BLOCK + tid;

    // z row in 16 float4 registers (literal indices only -> SROA-safe).
    float4 zf[16];
    {
        const float4* zp = (const float4*)(z_e + row * DIM);
#pragma unroll
        for (int i = 0; i < 16; ++i) zf[i] = zp[i];
    }

    float best = -INFINITY;
    int bestk = 0;

    for (int c = 0; c < KTOT; c += CHUNK) {
        // Stage CHUNK codebook rows: CHUNK*16 float4, coalesced.
        {
            const float4* eg = (const float4*)(emb + (size_t)c * DIM);
            float4* el = (float4*)e_lds;
#pragma unroll
            for (int i = 0; i < (CHUNK * DIM / 4) / BLOCK; ++i)
                el[tid + i * BLOCK] = eg[tid + i * BLOCK];
            if (tid < CHUNK) r_lds[tid] = inv_esq[c + tid];
        }
        __syncthreads();

#pragma unroll 2
        for (int kk = 0; kk < CHUNK; ++kk) {
            const float4* e4 = (const float4*)(e_lds + kk * DIM);  // uniform -> broadcast, 0 conflicts
            float a0 = 0.f, a1 = 0.f;
#pragma unroll
            for (int i = 0; i < 16; i += 2) {
                float4 v0 = e4[i];
                float4 v1 = e4[i + 1];
                a0 = fmaf(zf[i].x, v0.x, a0);
                a1 = fmaf(zf[i + 1].x, v1.x, a1);
                a0 = fmaf(zf[i].y, v0.y, a0);
                a1 = fmaf(zf[i + 1].y, v1.y, a1);
                a0 = fmaf(zf[i].z, v0.z, a0);
                a1 = fmaf(zf[i + 1].z, v1.z, a1);
                a0 = fmaf(zf[i].w, v0.w, a0);
                a1 = fmaf(zf[i + 1].w, v1.w, a1);
            }
            float dot = a0 + a1;
            // dist = (z_sq/e_sq[k]/(-2))*dot ; z_sq>0 => argmin dist == argmax dot/e_sq
            float q = dot * r_lds[kk];
            bool b = q > best;               // strict >: first-max == argmin-first
            bestk = b ? (c + kk) : bestk;
            best = fmaxf(q, best);
        }
        __syncthreads();
    }

    // Epilogue: gather z_q, straight-through output, loss partial.
    const float4* eb = (const float4*)(emb + (size_t)bestk * DIM);
    float4* oz = (float4*)(out_zq + row * DIM);
    float lsum = 0.f;
#pragma unroll
    for (int i = 0; i < 16; ++i) {
        float4 e = eb[i];
        float4 zz = zf[i];
        float dx = e.x - zz.x, dy = e.y - zz.y, dz = e.z - zz.z, dw = e.w - zz.w;
        float4 o;
        o.x = zz.x + dx;  // z_e + (z_q - z_e): matches reference rounding
        o.y = zz.y + dy;
        o.z = zz.z + dz;
        o.w = zz.w + dw;
        oz[i] = o;
        lsum = fmaf(dx, dx, lsum);
        lsum = fmaf(dy, dy, lsum);
        lsum = fmaf(dz, dz, lsum);
        lsum = fmaf(dw, dw, lsum);
    }
    out_idx[row] = (float)bestk;

    // Deterministic block reduction of loss partial (no atomics).
#pragma unroll
    for (int off = 32; off > 0; off >>= 1) lsum += __shfl_down(lsum, off);
    if ((tid & 63) == 0) wred[tid >> 6] = lsum;
    __syncthreads();
    if (tid == 0) partials[blockIdx.x] = (wred[0] + wred[1]) + (wred[2] + wred[3]);
}

__global__ __launch_bounds__(BLOCK) void vq_finalize(const float* __restrict__ partials,
                                                     float* __restrict__ out_loss) {
    __shared__ double wredd[BLOCK / 64];
    int tid = threadIdx.x;
    double s = 0.0;
    for (int i = tid; i < NROWS / BLOCK; i += BLOCK) s += (double)partials[i];
#pragma unroll
    for (int off = 32; off > 0; off >>= 1) s += __shfl_down(s, off);
    if ((tid & 63) == 0) wredd[tid >> 6] = s;
    __syncthreads();
    if (tid == 0) {
        double tot = (wredd[0] + wredd[1]) + (wredd[2] + wredd[3]);
        float m = (float)(tot / 16777216.0);   // mean over 64*4096*64 elements
        out_loss[0] = m + 0.25f * m;           // m + beta*m, matching reference order
    }
}

extern "C" void kernel_launch(void* const* d_in, const int* in_sizes, int n_in,
                              void* d_out, int out_size, void* d_ws, size_t ws_size,
                              hipStream_t stream) {
    const float* z_e = (const float*)d_in[0];
    const float* emb = (const float*)d_in[1];

    float* out = (float*)d_out;
    float* out_zq = out;                              // 16,777,216 floats
    float* out_idx = out + (size_t)NROWS * DIM;       // 262,144 floats (indices as float)
    float* out_loss = out_idx + NROWS;                // 1 float

    float* partials = (float*)d_ws;                   // 1024 floats
    float* inv_esq = partials + (NROWS / BLOCK);      // 1024 floats

    vq_prep<<<(KTOT + BLOCK - 1) / BLOCK, BLOCK, 0, stream>>>(emb, inv_esq);
    vq_main<<<NROWS / BLOCK, BLOCK, 0, stream>>>(z_e, emb, inv_esq, out_zq, out_idx, partials);
    vq_finalize<<<1, BLOCK, 0, stream>>>(partials, out_loss);
}

// Round 11
// 807.529 us; speedup vs baseline: 2.5443x; 1.3013x over previous
//
#include <hip/hip_runtime.h>
#include <math.h>

#define KTOT   1024
#define DIM    64
#define NROWS  (64 * 4096)
#define BLOCK  256
#define CHUNK  64
#define RPB    512                 // rows per block (2 per thread)
#define NPART  (NROWS / RPB)       // 512 loss partials

// ws layout: [0,512) float loss partials; [512,1536) float inv_esq

__global__ __launch_bounds__(BLOCK) void vq_prep(const float* __restrict__ emb,
                                                 float* __restrict__ inv_esq) {
    int k = blockIdx.x * BLOCK + threadIdx.x;
    if (k < KTOT) {
        const float4* e4 = (const float4*)(emb + (size_t)k * DIM);
        float s = 0.f;
#pragma unroll
        for (int i = 0; i < DIM / 4; ++i) {
            float4 v = e4[i];
            s += v.x * v.x;
            s += v.y * v.y;
            s += v.z * v.z;
            s += v.w * v.w;
        }
        inv_esq[k] = 1.0f / s;
    }
}

// r10 evidence: LDS-return-BW bound (68.7 GB broadcast traffic ~= 1.0 ms at
// 69 TB/s; occupancy-doubling was neutral). Register-block 2 rows/thread:
// each ds_read feeds 2 rows -> traffic halves. VALU floor ~234 µs.
__global__ __launch_bounds__(BLOCK) void vq_main(const float* __restrict__ z_e,
                                                 const float* __restrict__ emb,
                                                 const float* __restrict__ inv_esq,
                                                 float* __restrict__ out_zq,
                                                 float* __restrict__ out_idx,
                                                 float* __restrict__ partials) {
    __shared__ float e_lds[CHUNK * DIM];   // 16 KB codebook chunk
    __shared__ float r_lds[CHUNK];
    __shared__ float wred[BLOCK / 64];

    const int tid = threadIdx.x;
    const size_t row0 = (size_t)blockIdx.x * RPB + tid;
    const size_t row1 = row0 + BLOCK;

    // Two z rows in registers (literal indices only -> SROA-safe).
    float4 za[16], zb[16];
    {
        const float4* zp0 = (const float4*)(z_e + row0 * DIM);
        const float4* zp1 = (const float4*)(z_e + row1 * DIM);
#pragma unroll
        for (int i = 0; i < 16; ++i) za[i] = zp0[i];
#pragma unroll
        for (int i = 0; i < 16; ++i) zb[i] = zp1[i];
    }

    float best0 = -INFINITY, best1 = -INFINITY;
    int bk0 = 0, bk1 = 0;

    for (int c = 0; c < KTOT; c += CHUNK) {
        // Stage CHUNK codebook rows: 4 float4 per thread, coalesced.
        {
            const float4* eg = (const float4*)(emb + (size_t)c * DIM);
            float4* el = (float4*)e_lds;
#pragma unroll
            for (int i = 0; i < (CHUNK * DIM / 4) / BLOCK; ++i)
                el[tid + i * BLOCK] = eg[tid + i * BLOCK];
            if (tid < CHUNK) r_lds[tid] = inv_esq[c + tid];
        }
        __syncthreads();

        for (int kk = 0; kk < CHUNK; ++kk) {
            const float4* e4 = (const float4*)(e_lds + kk * DIM);  // uniform -> broadcast
            float a0 = 0.f, a1 = 0.f, b0 = 0.f, b1 = 0.f;
#pragma unroll
            for (int i = 0; i < 16; i += 2) {
                float4 v0 = e4[i];
                float4 v1 = e4[i + 1];
                a0 = fmaf(za[i].x, v0.x, a0);
                b0 = fmaf(zb[i].x, v0.x, b0);
                a1 = fmaf(za[i + 1].x, v1.x, a1);
                b1 = fmaf(zb[i + 1].x, v1.x, b1);
                a0 = fmaf(za[i].y, v0.y, a0);
                b0 = fmaf(zb[i].y, v0.y, b0);
                a1 = fmaf(za[i + 1].y, v1.y, a1);
                b1 = fmaf(zb[i + 1].y, v1.y, b1);
                a0 = fmaf(za[i].z, v0.z, a0);
                b0 = fmaf(zb[i].z, v0.z, b0);
                a1 = fmaf(za[i + 1].z, v1.z, a1);
                b1 = fmaf(zb[i + 1].z, v1.z, b1);
                a0 = fmaf(za[i].w, v0.w, a0);
                b0 = fmaf(zb[i].w, v0.w, b0);
                a1 = fmaf(za[i + 1].w, v1.w, a1);
                b1 = fmaf(zb[i + 1].w, v1.w, b1);
            }
            float r = r_lds[kk];
            float q0 = (a0 + a1) * r;       // argmin dist == argmax dot/e_sq
            float q1 = (b0 + b1) * r;
            bool s0 = q0 > best0;           // strict >: first-max == argmin-first
            bool s1 = q1 > best1;
            bk0 = s0 ? (c + kk) : bk0;
            bk1 = s1 ? (c + kk) : bk1;
            best0 = fmaxf(q0, best0);
            best1 = fmaxf(q1, best1);
        }
        __syncthreads();
    }

    // Epilogue: gather z_q, straight-through output, loss partials (both rows).
    float lsum = 0.f;
    {
        const float4* eb = (const float4*)(emb + (size_t)bk0 * DIM);
        float4* oz = (float4*)(out_zq + row0 * DIM);
#pragma unroll
        for (int i = 0; i < 16; ++i) {
            float4 e = eb[i];
            float4 zz = za[i];
            float dx = e.x - zz.x, dy = e.y - zz.y, dz = e.z - zz.z, dw = e.w - zz.w;
            float4 o;
            o.x = zz.x + dx;  // z_e + (z_q - z_e): matches reference rounding
            o.y = zz.y + dy;
            o.z = zz.z + dz;
            o.w = zz.w + dw;
            oz[i] = o;
            lsum = fmaf(dx, dx, lsum);
            lsum = fmaf(dy, dy, lsum);
            lsum = fmaf(dz, dz, lsum);
            lsum = fmaf(dw, dw, lsum);
        }
        out_idx[row0] = (float)bk0;
    }
    {
        const float4* eb = (const float4*)(emb + (size_t)bk1 * DIM);
        float4* oz = (float4*)(out_zq + row1 * DIM);
#pragma unroll
        for (int i = 0; i < 16; ++i) {
            float4 e = eb[i];
            float4 zz = zb[i];
            float dx = e.x - zz.x, dy = e.y - zz.y, dz = e.z - zz.z, dw = e.w - zz.w;
            float4 o;
            o.x = zz.x + dx;
            o.y = zz.y + dy;
            o.z = zz.z + dz;
            o.w = zz.w + dw;
            oz[i] = o;
            lsum = fmaf(dx, dx, lsum);
            lsum = fmaf(dy, dy, lsum);
            lsum = fmaf(dz, dz, lsum);
            lsum = fmaf(dw, dw, lsum);
        }
        out_idx[row1] = (float)bk1;
    }

    // Deterministic block reduction of loss partial (no atomics).
#pragma unroll
    for (int off = 32; off > 0; off >>= 1) lsum += __shfl_down(lsum, off);
    if ((tid & 63) == 0) wred[tid >> 6] = lsum;
    __syncthreads();
    if (tid == 0) partials[blockIdx.x] = (wred[0] + wred[1]) + (wred[2] + wred[3]);
}

__global__ __launch_bounds__(BLOCK) void vq_finalize(const float* __restrict__ partials,
                                                     float* __restrict__ out_loss) {
    __shared__ double wredd[BLOCK / 64];
    int tid = threadIdx.x;
    double s = 0.0;
    for (int i = tid; i < NPART; i += BLOCK) s += (double)partials[i];
#pragma unroll
    for (int off = 32; off > 0; off >>= 1) s += __shfl_down(s, off);
    if ((tid & 63) == 0) wredd[tid >> 6] = s;
    __syncthreads();
    if (tid == 0) {
        double tot = (wredd[0] + wredd[1]) + (wredd[2] + wredd[3]);
        float m = (float)(tot / 16777216.0);   // mean over 64*4096*64 elements
        out_loss[0] = m + 0.25f * m;           // m + beta*m, matching reference order
    }
}

extern "C" void kernel_launch(void* const* d_in, const int* in_sizes, int n_in,
                              void* d_out, int out_size, void* d_ws, size_t ws_size,
                              hipStream_t stream) {
    const float* z_e = (const float*)d_in[0];
    const float* emb = (const float*)d_in[1];

    float* out = (float*)d_out;
    float* out_zq = out;                              // 16,777,216 floats
    float* out_idx = out + (size_t)NROWS * DIM;       // 262,144 floats (indices as float)
    float* out_loss = out_idx + NROWS;                // 1 float

    float* partials = (float*)d_ws;                   // 512 floats
    float* inv_esq = partials + NPART;                // 1024 floats

    vq_prep<<<(KTOT + BLOCK - 1) / BLOCK, BLOCK, 0, stream>>>(emb, inv_esq);
    vq_main<<<NROWS / RPB, BLOCK, 0, stream>>>(z_e, emb, inv_esq, out_zq, out_idx, partials);
    vq_finalize<<<1, BLOCK, 0, stream>>>(partials, out_loss);
}

// Round 13
// 354.065 us; speedup vs baseline: 5.8029x; 2.2807x over previous
//
#include <hip/hip_runtime.h>
#include <math.h>
#include <stdint.h>

#define KTOT   1024
#define DIM    64
#define NROWS  (64 * 4096)

typedef __attribute__((ext_vector_type(8))) short  short8v;   // 8 bf16 (4 VGPR)
typedef __attribute__((ext_vector_type(8))) unsigned short ushort8v;
typedef __attribute__((ext_vector_type(4))) float  f32x4;

// RNE fp32 -> bf16 bits (no NaN/inf in this data)
__device__ __forceinline__ uint32_t f2bf(float f) {
    union { float f; uint32_t u; } c; c.f = f;
    return (c.u + 0x7fffu + ((c.u >> 16) & 1u)) >> 16;
}
__device__ __forceinline__ float bf2f(uint32_t b) {
    union { float f; uint32_t u; } c; c.u = b << 16; return c.f;
}

// ws: [0,4096) inv_esq (1024 f32); [4096, 4096+393216) bsplit (3 planes of
// [1024][64] bf16); then 1024 f32 loss partials. ~401 KB total.

__global__ __launch_bounds__(256) void vq_prep(const float* __restrict__ emb,
                                               float* __restrict__ inv_esq,
                                               unsigned short* __restrict__ bsplit) {
    int k = blockIdx.x * 256 + threadIdx.x;
    if (k >= KTOT) return;
    const float4* e4 = (const float4*)(emb + (size_t)k * DIM);
    float s = 0.f;
#pragma unroll
    for (int i = 0; i < 16; ++i) {
        float4 v = e4[i];
        s += v.x * v.x + v.y * v.y + v.z * v.z + v.w * v.w;
    }
    inv_esq[k] = 1.0f / s;
    // 3-way bf16 split planes: b1+b2+b3 == e to within 2^-26 rel.
#pragma unroll
    for (int c = 0; c < 8; ++c) {
        float4 va = e4[2 * c], vb = e4[2 * c + 1];
        float v[8] = {va.x, va.y, va.z, va.w, vb.x, vb.y, vb.z, vb.w};
        ushort8v w0, w1, w2;
#pragma unroll
        for (int j = 0; j < 8; ++j) {
            uint32_t q1 = f2bf(v[j]); float r1 = v[j] - bf2f(q1);
            uint32_t q2 = f2bf(r1);   float r2 = r1 - bf2f(q2);
            uint32_t q3 = f2bf(r2);
            w0[j] = (unsigned short)q1; w1[j] = (unsigned short)q2; w2[j] = (unsigned short)q3;
        }
        ((ushort8v*)(bsplit + ((size_t)0 * KTOT + k) * DIM))[c] = w0;
        ((ushort8v*)(bsplit + ((size_t)1 * KTOT + k) * DIM))[c] = w1;
        ((ushort8v*)(bsplit + ((size_t)2 * KTOT + k) * DIM))[c] = w2;
    }
}

// Fused split-GEMM + argmax. Wave = 64 rows (4 frags of 16); 64 col-tiles of
// 16 codes. A/B use the SAME (lane,j)->k formula (k = ks*32 + (lane>>4)*8 + j)
// so a shared k-permutation error cancels in the contraction. C/D layout per
// m89: col=lane&15, row=(lane>>4)*4+reg.
__global__ __launch_bounds__(256, 2) void vq_mfma(const float* __restrict__ z_e,
                                                  const unsigned short* __restrict__ bsplit,
                                                  const float* __restrict__ inv_esq,
                                                  float* __restrict__ out_idx) {
    const int tid = threadIdx.x;
    const int lane = tid & 63;
    const int l15 = lane & 15;
    const int lk = lane >> 4;
    const size_t wbase = (size_t)blockIdx.x * 256 + (tid >> 6) * 64;

    // Load z rows and 3-way split in-register: A[rf][ks][s]
    short8v A[4][2][3];
#pragma unroll
    for (int rf = 0; rf < 4; ++rf) {
        const size_t row = wbase + rf * 16 + l15;      // A row = lane&15
#pragma unroll
        for (int ks = 0; ks < 2; ++ks) {
            const float4* p = (const float4*)(z_e + row * DIM + ks * 32 + lk * 8);
            float4 pa = p[0], pb = p[1];
            float v[8] = {pa.x, pa.y, pa.z, pa.w, pb.x, pb.y, pb.z, pb.w};
            short8v s0, s1, s2;
#pragma unroll
            for (int j = 0; j < 8; ++j) {
                uint32_t q1 = f2bf(v[j]); float r1 = v[j] - bf2f(q1);
                uint32_t q2 = f2bf(r1);   float r2 = r1 - bf2f(q2);
                uint32_t q3 = f2bf(r2);
                s0[j] = (short)q1; s1[j] = (short)q2; s2[j] = (short)q3;
            }
            A[rf][ks][0] = s0; A[rf][ks][1] = s1; A[rf][ks][2] = s2;
        }
    }

    float rv[4][4];
    int   ri[4][4];
#pragma unroll
    for (int a = 0; a < 4; ++a)
#pragma unroll
        for (int b = 0; b < 4; ++b) { rv[a][b] = -INFINITY; ri[a][b] = 0; }

#pragma unroll 2
    for (int ct = 0; ct < 64; ++ct) {
        const int col = ct * 16 + l15;
        short8v B[2][3];
#pragma unroll
        for (int ks = 0; ks < 2; ++ks)
#pragma unroll
            for (int t = 0; t < 3; ++t)
                B[ks][t] = *(const short8v*)(bsplit + ((size_t)t * KTOT + col) * DIM + ks * 32 + lk * 8);
        const float inv = inv_esq[col];
#pragma unroll
        for (int rf = 0; rf < 4; ++rf) {
            f32x4 acc = {0.f, 0.f, 0.f, 0.f};
#pragma unroll
            for (int ks = 0; ks < 2; ++ks) {
                // products: (1,1); (1,2)+(2,1); (2,2)+(1,3)+(3,1)  [magnitudes 1, 2^-8, 2^-16]
                acc = __builtin_amdgcn_mfma_f32_16x16x32_bf16(A[rf][ks][0], B[ks][0], acc, 0, 0, 0);
                acc = __builtin_amdgcn_mfma_f32_16x16x32_bf16(A[rf][ks][0], B[ks][1], acc, 0, 0, 0);
                acc = __builtin_amdgcn_mfma_f32_16x16x32_bf16(A[rf][ks][1], B[ks][0], acc, 0, 0, 0);
                acc = __builtin_amdgcn_mfma_f32_16x16x32_bf16(A[rf][ks][1], B[ks][1], acc, 0, 0, 0);
                acc = __builtin_amdgcn_mfma_f32_16x16x32_bf16(A[rf][ks][0], B[ks][2], acc, 0, 0, 0);
                acc = __builtin_amdgcn_mfma_f32_16x16x32_bf16(A[rf][ks][2], B[ks][0], acc, 0, 0, 0);
            }
#pragma unroll
            for (int r = 0; r < 4; ++r) {
                float q = acc[r] * inv;        // argmin dist == argmax dot/e_sq
                bool u = q > rv[rf][r];        // strict >: first (lowest k) wins ties
                ri[rf][r] = u ? col : ri[rf][r];
                rv[rf][r] = fmaxf(q, rv[rf][r]);
            }
        }
    }

    // Reduce over the 16 col-lanes; lower-k wins exact ties.
#pragma unroll
    for (int rf = 0; rf < 4; ++rf)
#pragma unroll
        for (int r = 0; r < 4; ++r) {
            float v = rv[rf][r];
            int  kk = ri[rf][r];
#pragma unroll
            for (int m = 1; m < 16; m <<= 1) {
                float ov = __shfl_xor(v, m, 64);
                int   ok = __shfl_xor(kk, m, 64);
                if (ov > v || (ov == v && ok < kk)) { v = ov; kk = ok; }
            }
            if (l15 == 0) out_idx[wbase + rf * 16 + lk * 4 + r] = (float)kk;
        }
}

__global__ __launch_bounds__(256) void vq_epi(const float* __restrict__ z_e,
                                              const float* __restrict__ emb,
                                              const float* __restrict__ idxf,
                                              float* __restrict__ out_zq,
                                              float* __restrict__ partials) {
    __shared__ float wred[4];
    const int tid = threadIdx.x;
    const size_t row = (size_t)blockIdx.x * 256 + tid;
    const int k = (int)idxf[row];
    const float4* zp = (const float4*)(z_e + row * DIM);
    const float4* ep = (const float4*)(emb + (size_t)k * DIM);
    float4* op = (float4*)(out_zq + row * DIM);
    float lsum = 0.f;
#pragma unroll
    for (int i = 0; i < 16; ++i) {
        float4 z = zp[i], e = ep[i];
        float dx = e.x - z.x, dy = e.y - z.y, dz = e.z - z.z, dw = e.w - z.w;
        float4 o;
        o.x = z.x + dx;  // z_e + (z_q - z_e): matches reference rounding
        o.y = z.y + dy;
        o.z = z.z + dz;
        o.w = z.w + dw;
        op[i] = o;
        lsum = fmaf(dx, dx, lsum);
        lsum = fmaf(dy, dy, lsum);
        lsum = fmaf(dz, dz, lsum);
        lsum = fmaf(dw, dw, lsum);
    }
#pragma unroll
    for (int off = 32; off > 0; off >>= 1) lsum += __shfl_down(lsum, off);
    if ((tid & 63) == 0) wred[tid >> 6] = lsum;
    __syncthreads();
    if (tid == 0) partials[blockIdx.x] = (wred[0] + wred[1]) + (wred[2] + wred[3]);
}

__global__ __launch_bounds__(256) void vq_finalize(const float* __restrict__ partials,
                                                   float* __restrict__ out_loss) {
    __shared__ double wredd[4];
    int tid = threadIdx.x;
    double s = 0.0;
    for (int i = tid; i < 1024; i += 256) s += (double)partials[i];
#pragma unroll
    for (int off = 32; off > 0; off >>= 1) s += __shfl_down(s, off);
    if ((tid & 63) == 0) wredd[tid >> 6] = s;
    __syncthreads();
    if (tid == 0) {
        double tot = (wredd[0] + wredd[1]) + (wredd[2] + wredd[3]);
        float m = (float)(tot / 16777216.0);   // mean over 64*4096*64 elements
        out_loss[0] = m + 0.25f * m;           // m + beta*m, matching reference order
    }
}

extern "C" void kernel_launch(void* const* d_in, const int* in_sizes, int n_in,
                              void* d_out, int out_size, void* d_ws, size_t ws_size,
                              hipStream_t stream) {
    const float* z_e = (const float*)d_in[0];
    const float* emb = (const float*)d_in[1];

    float* out = (float*)d_out;
    float* out_zq = out;                              // 16,777,216 floats
    float* out_idx = out + (size_t)NROWS * DIM;       // 262,144 floats (indices as float)
    float* out_loss = out_idx + NROWS;                // 1 float

    char* ws = (char*)d_ws;
    float* inv_esq = (float*)ws;                                  // 1024 f32
    unsigned short* bsplit = (unsigned short*)(ws + 4096);        // 3*1024*64 bf16
    float* partials = (float*)(ws + 4096 + 3 * KTOT * DIM * 2);   // 1024 f32

    vq_prep<<<4, 256, 0, stream>>>(emb, inv_esq, bsplit);
    vq_mfma<<<NROWS / 256, 256, 0, stream>>>(z_e, bsplit, inv_esq, out_idx);
    vq_epi<<<NROWS / 256, 256, 0, stream>>>(z_e, emb, out_idx, out_zq, partials);
    vq_finalize<<<1, 256, 0, stream>>>(partials, out_loss);
}